// Round 7
// baseline (466.313 us; speedup 1.0000x reference)
//
#include <hip/hip_runtime.h>
#include <hip/hip_bf16.h>

typedef unsigned short u16;
typedef unsigned int u32;
typedef __attribute__((ext_vector_type(8))) short short8;
typedef __attribute__((ext_vector_type(4))) float f32x4;

#define NN 8192
#define KIN 256
#define FOUT 128
#define SPLITS 8
#define KPER (NN / SPLITS)   // 1024
#define KSTEPS (KPER / 32)   // 32 k-steps of 32 per split
#define L2E 1.4426950408889634f

__device__ __forceinline__ float exp2fast(float x) { return __builtin_amdgcn_exp2f(x); }

__device__ __forceinline__ u16 f2bf(float f) {
    u32 u = __float_as_uint(f);
    u32 r = ((u >> 16) & 1u) + 0x7fffu;
    return (u16)((u + r) >> 16);
}
__device__ __forceinline__ u32 pk_bf16(float a, float b) {
    union { __hip_bfloat162 h2; u32 u; } cv;
    cv.h2 = __float22bfloat162_rn(make_float2(a, b));   // v_cvt_pk_bf16_f32
    return cv.u;
}
__device__ __forceinline__ u32 fkey(float f) {
    u32 b = __float_as_uint(f);
    return (b & 0x80000000u) ? ~b : (b | 0x80000000u);
}
__device__ __forceinline__ float funkey(u32 k) {
    u32 b = (k & 0x80000000u) ? (k & 0x7fffffffu) : ~k;
    return __uint_as_float(b);
}

// ---------------- K1: Wh = h@W (fp32 acc) -> whfrag (B-fragment-major bf16), src, dst*log2e, gmax
// whfrag layout: [(kstep*8 + ntile)*64 + lane] * 8 u16, element j = Wh[kstep*32 + (lane>>4)*8 + j][ntile*16 + (lane&15)]
__global__ __launch_bounds__(256) void k1_wh(
    const float* __restrict__ h, const float* __restrict__ W, const float* __restrict__ a,
    u16* __restrict__ whfrag,
    float* __restrict__ src, float* __restrict__ dl2e, u32* __restrict__ gmaxk)
{
    __shared__ float hT[64][36];
    __shared__ u16   lt[128][40];    // [feature][node] bf16 tile, 80B row stride
    __shared__ float sd[32][2];
    const int t  = threadIdx.x;
    const int m0 = blockIdx.x * 32;  // node block; kstep = blockIdx.x
    const int rq = t >> 5, cq = t & 31;

    float acc[4][4];
#pragma unroll
    for (int i = 0; i < 4; i++)
#pragma unroll
        for (int j = 0; j < 4; j++) acc[i][j] = 0.f;
    if (t < 64) sd[t >> 1][t & 1] = 0.f;

    for (int kt = 0; kt < KIN; kt += 64) {
        __syncthreads();
#pragma unroll
        for (int s2 = 0; s2 < 2; s2++) {
            int f = s2 * 256 + t;
            int r = f >> 4, kc = (f & 15) * 4;
            float4 hv = *(const float4*)(h + (size_t)(m0 + r) * KIN + kt + kc);
            hT[kc + 0][r] = hv.x; hT[kc + 1][r] = hv.y;
            hT[kc + 2][r] = hv.z; hT[kc + 3][r] = hv.w;
        }
        __syncthreads();
        for (int k = 0; k < 64; k++) {
            float4 wv = *(const float4*)(W + (size_t)(kt + k) * FOUT + cq * 4);
            float h0 = hT[k][rq * 4 + 0], h1 = hT[k][rq * 4 + 1];
            float h2 = hT[k][rq * 4 + 2], h3 = hT[k][rq * 4 + 3];
            acc[0][0] += h0 * wv.x; acc[0][1] += h0 * wv.y; acc[0][2] += h0 * wv.z; acc[0][3] += h0 * wv.w;
            acc[1][0] += h1 * wv.x; acc[1][1] += h1 * wv.y; acc[1][2] += h1 * wv.z; acc[1][3] += h1 * wv.w;
            acc[2][0] += h2 * wv.x; acc[2][1] += h2 * wv.y; acc[2][2] += h2 * wv.z; acc[2][3] += h2 * wv.w;
            acc[3][0] += h3 * wv.x; acc[3][1] += h3 * wv.y; acc[3][2] += h3 * wv.z; acc[3][3] += h3 * wv.w;
        }
    }
#pragma unroll
    for (int i = 0; i < 4; i++) {
        float sp = 0.f, dp = 0.f;
#pragma unroll
        for (int j = 0; j < 4; j++) {
            sp += acc[i][j] * a[cq * 4 + j];
            dp += acc[i][j] * a[FOUT + cq * 4 + j];
            lt[cq * 4 + j][rq * 4 + i] = f2bf(acc[i][j]);
        }
        atomicAdd(&sd[rq * 4 + i][0], sp);
        atomicAdd(&sd[rq * 4 + i][1], dp);
    }
    __syncthreads();
    if (t < 32) { src[m0 + t] = sd[t][0]; dl2e[m0 + t] = sd[t][1] * L2E; }
    if (t < 64) {
        float v = (t < 32) ? sd[t][1] : -3.0e38f;
#pragma unroll
        for (int off = 32; off >= 1; off >>= 1) v = fmaxf(v, __shfl_down(v, off));
        if (t == 0) atomicMax(gmaxk, fkey(v));
    }
    const int kstep = blockIdx.x;
#pragma unroll
    for (int p = 0; p < 2; p++) {
        int f = p * 256 + t;         // 0..511
        int nt = f >> 6;             // 0..7
        int l  = f & 63;
        short8 v = *(const short8*)&lt[nt * 16 + (l & 15)][(l >> 4) * 8];
        *(short8*)(whfrag + ((size_t)(kstep * 8 + nt) * 64 + l) * 8) = v;
    }
}

// ---------------- K2: barrier-free, coalesced-adj flash attention -------------------
// Wave = 16-row strip. adj loaded coalesced (lane = row lane>>3 [+8], cols (lane&7)*4),
// P computed in that layout, transposed to A-fragment layout via wave-PRIVATE LDS
// (no __syncthreads anywhere -> no vmcnt(0) barrier drains).
__global__ __launch_bounds__(256, 4) void k2_attn(
    const int* __restrict__ adj, const float* __restrict__ src, const float* __restrict__ dl2e,
    const u16* __restrict__ whfrag, const u32* __restrict__ gmaxk,
    float* __restrict__ accp, float* __restrict__ lp)
{
    __shared__ u16 Pall[4][16][40];              // per-wave private 16x32 bf16 tile (80B rows)
    const int t = threadIdx.x;
    const int lane = t & 63, wave = t >> 6;
    u16 (*P)[40] = Pall[wave];
    const int strip = blockIdx.x * 4 + wave;     // 0..511
    const int i0 = strip * 16;
    const int split = blockIdx.y;
    const int l15 = lane & 15, quad = lane >> 4;
    const int r0 = lane >> 3;                    // rows this lane computes (coalesced layout)
    const int r1 = 8 + r0;
    const int co = (lane & 7) * 4;               // col offset within 32-step

    const float gm = funkey(*gmaxk) * L2E;
    float s0 = src[i0 + r0] * L2E, s1 = src[i0 + r1] * L2E;
    float xm0 = s0 + gm, xm1 = s1 + gm;
    float C0 = fmaxf(xm0, 0.01f * xm0), C1 = fmaxf(xm1, 0.01f * xm1);
    const float y10 = s0 - C0, y20 = 0.01f * s0 - C0;
    const float y11 = s1 - C1, y21 = 0.01f * s1 - C1;

    const int* arow0 = adj + (size_t)(i0 + r0) * NN + co;
    const int* arow1 = adj + (size_t)(i0 + r1) * NN + co;
    const int st0 = blockIdx.x & (KSTEPS - 1);
    const int kbase = split * KPER;

    f32x4 acc[8];
#pragma unroll
    for (int nt = 0; nt < 8; nt++) acc[nt] = {0.f, 0.f, 0.f, 0.f};
    float ps0 = 0.f, ps1 = 0.f;

    // depth-2 register prefetch (adj x2 rows + dst), all coalesced
    int4 a0s[2], a1s[2]; float4 dvs[2];
#pragma unroll
    for (int s = 0; s < 2; s++) {
        int kb = kbase + ((st0 + s) & (KSTEPS - 1)) * 32;
        a0s[s] = *(const int4*)(arow0 + kb);
        a1s[s] = *(const int4*)(arow1 + kb);
        dvs[s] = *(const float4*)(dl2e + kb + co);
    }

#pragma unroll 4
    for (int it = 0; it < KSTEPS; ++it) {
        const int sl = it & 1;
        const int kb = kbase + ((st0 + it) & (KSTEPS - 1)) * 32;

        // B fragments first (L2 latency hidden under P compute + LDS roundtrip)
        uint4 bv[8];
        const u16* wf = whfrag + ((size_t)(kb >> 5) * 8 * 64 + lane) * 8;
#pragma unroll
        for (int nt = 0; nt < 8; nt++)
            bv[nt] = *(const uint4*)(wf + (size_t)nt * 64 * 8);

        // P for (r0, co..co+3) and (r1, co..co+3)
        int4 a0 = a0s[sl], a1 = a1s[sl];
        float4 d = dvs[sl];
        {
            float x, p0, p1, p2, p3;
            x = fmaxf(y10 + d.x, y20 + 0.01f * d.x); p0 = exp2fast(a0.x > 0 ? x : -1.0e9f);
            x = fmaxf(y10 + d.y, y20 + 0.01f * d.y); p1 = exp2fast(a0.y > 0 ? x : -1.0e9f);
            x = fmaxf(y10 + d.z, y20 + 0.01f * d.z); p2 = exp2fast(a0.z > 0 ? x : -1.0e9f);
            x = fmaxf(y10 + d.w, y20 + 0.01f * d.w); p3 = exp2fast(a0.w > 0 ? x : -1.0e9f);
            ps0 += (p0 + p1) + (p2 + p3);
            *(uint2*)&P[r0][co] = make_uint2(pk_bf16(p0, p1), pk_bf16(p2, p3));
            x = fmaxf(y11 + d.x, y21 + 0.01f * d.x); p0 = exp2fast(a1.x > 0 ? x : -1.0e9f);
            x = fmaxf(y11 + d.y, y21 + 0.01f * d.y); p1 = exp2fast(a1.y > 0 ? x : -1.0e9f);
            x = fmaxf(y11 + d.z, y21 + 0.01f * d.z); p2 = exp2fast(a1.z > 0 ? x : -1.0e9f);
            x = fmaxf(y11 + d.w, y21 + 0.01f * d.w); p3 = exp2fast(a1.w > 0 ? x : -1.0e9f);
            ps1 += (p0 + p1) + (p2 + p3);
            *(uint2*)&P[r1][co] = make_uint2(pk_bf16(p0, p1), pk_bf16(p2, p3));
        }

        // prefetch it+2 into this slot (wrapped: always valid, branchless)
        {
            int kb2 = kbase + ((st0 + it + 2) & (KSTEPS - 1)) * 32;
            a0s[sl] = *(const int4*)(arow0 + kb2);
            a1s[sl] = *(const int4*)(arow1 + kb2);
            dvs[sl] = *(const float4*)(dl2e + kb2 + co);
        }

        // A fragment via wave-private LDS transpose (same-wave DS ops are ordered)
        short8 af = *(const short8*)&P[l15][quad * 8];

#pragma unroll
        for (int nt = 0; nt < 8; nt++) {
            union { uint4 q; short8 s8; } bf; bf.q = bv[nt];
            acc[nt] = __builtin_amdgcn_mfma_f32_16x16x32_bf16(af, bf.s8, acc[nt], 0, 0, 0);
        }
    }

    // row sums: reduce over the 8 lanes (chunks) covering each row
    ps0 += __shfl_down(ps0, 4, 8); ps0 += __shfl_down(ps0, 2, 8); ps0 += __shfl_down(ps0, 1, 8);
    ps1 += __shfl_down(ps1, 4, 8); ps1 += __shfl_down(ps1, 2, 8); ps1 += __shfl_down(ps1, 1, 8);
    if ((lane & 7) == 0) {
        lp[split * NN + i0 + r0] = ps0;
        lp[split * NN + i0 + r1] = ps1;
    }

    // accumulator partials, lane-major tile layout (fully coalesced)
    float* ab = accp + (size_t)split * (NN * FOUT);
#pragma unroll
    for (int nt = 0; nt < 8; nt++)
        *(f32x4*)&ab[((size_t)(strip * 8 + nt) * 64 + lane) * 4] = acc[nt];
}

// ---------------- K2b: inverse row sums --------------------------------------------
__global__ __launch_bounds__(256) void k2b_rsum(const float* __restrict__ lp,
                                               float* __restrict__ rinv)
{
    int i = blockIdx.x * 256 + threadIdx.x;
    float s = 0.f;
#pragma unroll
    for (int sp = 0; sp < SPLITS; sp++) s += lp[sp * NN + i];
    rinv[i] = 1.0f / s;
}

// ---------------- K3: combine splits from tile layout, normalize, store ------------
__global__ __launch_bounds__(256) void k3_comb(
    const float* __restrict__ accp, const float* __restrict__ rinv, float* __restrict__ out)
{
    int idx = blockIdx.x * 256 + threadIdx.x;   // float4 index over tile storage
    int tile = idx >> 6, l = idx & 63;
    float4 s = make_float4(0.f, 0.f, 0.f, 0.f);
#pragma unroll
    for (int sp = 0; sp < SPLITS; sp++) {
        float4 v = *(const float4*)(accp + (size_t)sp * (NN * FOUT) + (size_t)idx * 4);
        s.x += v.x; s.y += v.y; s.z += v.z; s.w += v.w;
    }
    int row0 = (tile >> 3) * 16 + (l >> 4) * 4;
    int col  = (tile & 7) * 16 + (l & 15);
    float4 ri = *(const float4*)(rinv + row0);
    out[(size_t)(row0 + 0) * FOUT + col] = s.x * ri.x;
    out[(size_t)(row0 + 1) * FOUT + col] = s.y * ri.y;
    out[(size_t)(row0 + 2) * FOUT + col] = s.z * ri.z;
    out[(size_t)(row0 + 3) * FOUT + col] = s.w * ri.w;
}

extern "C" void kernel_launch(void* const* d_in, const int* in_sizes, int n_in,
                              void* d_out, int out_size, void* d_ws, size_t ws_size,
                              hipStream_t stream) {
    const float* h   = (const float*)d_in[0];
    const int*   adj = (const int*)d_in[1];
    const float* W   = (const float*)d_in[2];
    const float* a   = (const float*)d_in[3];
    float* out = (float*)d_out;

    char* ws = (char*)d_ws;
    u16*   whfrag = (u16*)ws;                           // 2 MB
    float* src    = (float*)(ws + (2u << 20));          // 32 KB
    float* dl2e   = src + NN;                           // 32 KB
    u32*   gmaxk  = (u32*)(dl2e + NN);                  // 4 B
    float* accp   = (float*)(ws + (3u << 20));          // 32 MB
    float* lp     = (float*)(ws + (35u << 20));         // 256 KB
    float* rinv   = (float*)(ws + (36u << 20));         // 32 KB

    (void)hipMemsetAsync(gmaxk, 0, sizeof(u32), stream);
    k1_wh<<<dim3(NN / 32), dim3(256), 0, stream>>>(h, W, a, whfrag, src, dl2e, gmaxk);
    k2_attn<<<dim3(NN / 64, SPLITS), dim3(256), 0, stream>>>(adj, src, dl2e, whfrag, gmaxk, accp, lp);
    k2b_rsum<<<dim3(NN / 256), dim3(256), 0, stream>>>(lp, rinv);
    k3_comb<<<dim3((NN * FOUT / 4) / 256), dim3(256), 0, stream>>>(accp, rinv, out);
}

// Round 8
// 463.637 us; speedup vs baseline: 1.0058x; 1.0058x over previous
//
#include <hip/hip_runtime.h>
#include <hip/hip_bf16.h>

typedef unsigned short u16;
typedef unsigned char u8;
typedef unsigned int u32;
typedef __attribute__((ext_vector_type(8))) short short8;
typedef __attribute__((ext_vector_type(4))) float f32x4;

#define NN 8192
#define KIN 256
#define FOUT 128
#define SPLITS 8
#define KPER (NN / SPLITS)   // 1024
#define KSTEPS (KPER / 32)   // 32 k-steps of 32 per split
#define L2E 1.4426950408889634f

__device__ __forceinline__ float exp2fast(float x) { return __builtin_amdgcn_exp2f(x); }

__device__ __forceinline__ u16 f2bf(float f) {
    u32 u = __float_as_uint(f);
    u32 r = ((u >> 16) & 1u) + 0x7fffu;
    return (u16)((u + r) >> 16);
}
__device__ __forceinline__ u32 pk_bf16(float a, float b) {
    union { __hip_bfloat162 h2; u32 u; } cv;
    cv.h2 = __float22bfloat162_rn(make_float2(a, b));   // v_cvt_pk_bf16_f32
    return cv.u;
}
__device__ __forceinline__ u32 fkey(float f) {
    u32 b = __float_as_uint(f);
    return (b & 0x80000000u) ? ~b : (b | 0x80000000u);
}
__device__ __forceinline__ float funkey(u32 k) {
    u32 b = (k & 0x80000000u) ? (k & 0x7fffffffu) : ~k;
    return __uint_as_float(b);
}

// ---------------- K0: adj int32 -> nibble-map (1 byte per 4 cols), dense sequential --
// The ONLY pass over the 256 MB adj, in fill-like sequential order (1KB/wave reads,
// 64B/wave writes). bm[i*2048 + c/4] bit (c&3) = adj[i][c] > 0.
__global__ __launch_bounds__(256) void k0_pack(const int* __restrict__ adj,
                                              u8* __restrict__ bm)
{
    size_t idx = (size_t)blockIdx.x * 256 + threadIdx.x;   // over N*N/4 = 16M bytes
    int4 v = *(const int4*)(adj + idx * 4);
    bm[idx] = (u8)((v.x > 0) | ((v.y > 0) << 1) | ((v.z > 0) << 2) | ((v.w > 0) << 3));
}

// ---------------- K1: Wh = h@W (fp32 acc) -> whfrag (B-fragment-major bf16), src, dst*log2e, gmax
__global__ __launch_bounds__(256) void k1_wh(
    const float* __restrict__ h, const float* __restrict__ W, const float* __restrict__ a,
    u16* __restrict__ whfrag,
    float* __restrict__ src, float* __restrict__ dl2e, u32* __restrict__ gmaxk)
{
    __shared__ float hT[64][36];
    __shared__ u16   lt[128][40];    // [feature][node] bf16 tile, 80B row stride
    __shared__ float sd[32][2];
    const int t  = threadIdx.x;
    const int m0 = blockIdx.x * 32;  // node block; kstep = blockIdx.x
    const int rq = t >> 5, cq = t & 31;

    float acc[4][4];
#pragma unroll
    for (int i = 0; i < 4; i++)
#pragma unroll
        for (int j = 0; j < 4; j++) acc[i][j] = 0.f;
    if (t < 64) sd[t >> 1][t & 1] = 0.f;

    for (int kt = 0; kt < KIN; kt += 64) {
        __syncthreads();
#pragma unroll
        for (int s2 = 0; s2 < 2; s2++) {
            int f = s2 * 256 + t;
            int r = f >> 4, kc = (f & 15) * 4;
            float4 hv = *(const float4*)(h + (size_t)(m0 + r) * KIN + kt + kc);
            hT[kc + 0][r] = hv.x; hT[kc + 1][r] = hv.y;
            hT[kc + 2][r] = hv.z; hT[kc + 3][r] = hv.w;
        }
        __syncthreads();
        for (int k = 0; k < 64; k++) {
            float4 wv = *(const float4*)(W + (size_t)(kt + k) * FOUT + cq * 4);
            float h0 = hT[k][rq * 4 + 0], h1 = hT[k][rq * 4 + 1];
            float h2 = hT[k][rq * 4 + 2], h3 = hT[k][rq * 4 + 3];
            acc[0][0] += h0 * wv.x; acc[0][1] += h0 * wv.y; acc[0][2] += h0 * wv.z; acc[0][3] += h0 * wv.w;
            acc[1][0] += h1 * wv.x; acc[1][1] += h1 * wv.y; acc[1][2] += h1 * wv.z; acc[1][3] += h1 * wv.w;
            acc[2][0] += h2 * wv.x; acc[2][1] += h2 * wv.y; acc[2][2] += h2 * wv.z; acc[2][3] += h2 * wv.w;
            acc[3][0] += h3 * wv.x; acc[3][1] += h3 * wv.y; acc[3][2] += h3 * wv.z; acc[3][3] += h3 * wv.w;
        }
    }
#pragma unroll
    for (int i = 0; i < 4; i++) {
        float sp = 0.f, dp = 0.f;
#pragma unroll
        for (int j = 0; j < 4; j++) {
            sp += acc[i][j] * a[cq * 4 + j];
            dp += acc[i][j] * a[FOUT + cq * 4 + j];
            lt[cq * 4 + j][rq * 4 + i] = f2bf(acc[i][j]);
        }
        atomicAdd(&sd[rq * 4 + i][0], sp);
        atomicAdd(&sd[rq * 4 + i][1], dp);
    }
    __syncthreads();
    if (t < 32) { src[m0 + t] = sd[t][0]; dl2e[m0 + t] = sd[t][1] * L2E; }
    if (t < 64) {
        float v = (t < 32) ? sd[t][1] : -3.0e38f;
#pragma unroll
        for (int off = 32; off >= 1; off >>= 1) v = fmaxf(v, __shfl_down(v, off));
        if (t == 0) atomicMax(gmaxk, fkey(v));
    }
    const int kstep = blockIdx.x;
#pragma unroll
    for (int p = 0; p < 2; p++) {
        int f = p * 256 + t;         // 0..511
        int nt = f >> 6;             // 0..7
        int l  = f & 63;
        short8 v = *(const short8*)&lt[nt * 16 + (l & 15)][(l >> 4) * 8];
        *(short8*)(whfrag + ((size_t)(kstep * 8 + nt) * 64 + l) * 8) = v;
    }
}

// ---------------- K2: barrier-free flash attention over the nibble-map --------------
// Wave = 16-row strip, no __syncthreads. adj mask read as 2 bytes/lane/iter from the
// L3-resident 16 MB nibble-map. P transposed to A-fragment layout via wave-private LDS.
__global__ __launch_bounds__(256, 4) void k2_attn(
    const u8* __restrict__ bm, const float* __restrict__ src, const float* __restrict__ dl2e,
    const u16* __restrict__ whfrag, const u32* __restrict__ gmaxk,
    float* __restrict__ accp, float* __restrict__ lp)
{
    __shared__ u16 Pall[4][16][40];              // per-wave private 16x32 bf16 tile
    const int t = threadIdx.x;
    const int lane = t & 63, wave = t >> 6;
    u16 (*P)[40] = Pall[wave];
    const int strip = blockIdx.x * 4 + wave;     // 0..511
    const int i0 = strip * 16;
    const int split = blockIdx.y;
    const int l15 = lane & 15, quad = lane >> 4;
    const int r0 = lane >> 3;                    // rows this lane computes
    const int r1 = 8 + r0;
    const int co = (lane & 7) * 4;               // col offset within 32-step

    const float gm = funkey(*gmaxk) * L2E;
    float s0 = src[i0 + r0] * L2E, s1 = src[i0 + r1] * L2E;
    float xm0 = s0 + gm, xm1 = s1 + gm;
    float C0 = fmaxf(xm0, 0.01f * xm0), C1 = fmaxf(xm1, 0.01f * xm1);
    const float y10 = s0 - C0, y20 = 0.01f * s0 - C0;
    const float y11 = s1 - C1, y21 = 0.01f * s1 - C1;

    const u8* brow0 = bm + (size_t)(i0 + r0) * (NN / 4) + (lane & 7);
    const u8* brow1 = bm + (size_t)(i0 + r1) * (NN / 4) + (lane & 7);
    const int st0 = blockIdx.x & (KSTEPS - 1);
    const int kbase = split * KPER;

    f32x4 acc[8];
#pragma unroll
    for (int nt = 0; nt < 8; nt++) acc[nt] = {0.f, 0.f, 0.f, 0.f};
    float ps0 = 0.f, ps1 = 0.f;

    // depth-2 register prefetch (nibbles + dst)
    u32 n0s[2], n1s[2]; float4 dvs[2];
#pragma unroll
    for (int s = 0; s < 2; s++) {
        int kb = kbase + ((st0 + s) & (KSTEPS - 1)) * 32;
        n0s[s] = brow0[kb >> 2];
        n1s[s] = brow1[kb >> 2];
        dvs[s] = *(const float4*)(dl2e + kb + co);
    }

#pragma unroll 4
    for (int it = 0; it < KSTEPS; ++it) {
        const int sl = it & 1;
        const int kb = kbase + ((st0 + it) & (KSTEPS - 1)) * 32;

        // B fragments first (L2 latency hidden under P compute + LDS roundtrip)
        uint4 bv[8];
        const u16* wf = whfrag + ((size_t)(kb >> 5) * 8 * 64 + lane) * 8;
#pragma unroll
        for (int nt = 0; nt < 8; nt++)
            bv[nt] = *(const uint4*)(wf + (size_t)nt * 64 * 8);

        // P for (r0, co..co+3) and (r1, co..co+3); mask from nibble bits
        u32 n0 = n0s[sl], n1 = n1s[sl];
        float4 d = dvs[sl];
        {
            float x, p0, p1, p2, p3;
            x = fmaxf(y10 + d.x, y20 + 0.01f * d.x); p0 = exp2fast((n0 & 1u) ? x : -1.0e9f);
            x = fmaxf(y10 + d.y, y20 + 0.01f * d.y); p1 = exp2fast((n0 & 2u) ? x : -1.0e9f);
            x = fmaxf(y10 + d.z, y20 + 0.01f * d.z); p2 = exp2fast((n0 & 4u) ? x : -1.0e9f);
            x = fmaxf(y10 + d.w, y20 + 0.01f * d.w); p3 = exp2fast((n0 & 8u) ? x : -1.0e9f);
            ps0 += (p0 + p1) + (p2 + p3);
            *(uint2*)&P[r0][co] = make_uint2(pk_bf16(p0, p1), pk_bf16(p2, p3));
            x = fmaxf(y11 + d.x, y21 + 0.01f * d.x); p0 = exp2fast((n1 & 1u) ? x : -1.0e9f);
            x = fmaxf(y11 + d.y, y21 + 0.01f * d.y); p1 = exp2fast((n1 & 2u) ? x : -1.0e9f);
            x = fmaxf(y11 + d.z, y21 + 0.01f * d.z); p2 = exp2fast((n1 & 4u) ? x : -1.0e9f);
            x = fmaxf(y11 + d.w, y21 + 0.01f * d.w); p3 = exp2fast((n1 & 8u) ? x : -1.0e9f);
            ps1 += (p0 + p1) + (p2 + p3);
            *(uint2*)&P[r1][co] = make_uint2(pk_bf16(p0, p1), pk_bf16(p2, p3));
        }

        // prefetch it+2 into this slot (wrapped: always valid, branchless)
        {
            int kb2 = kbase + ((st0 + it + 2) & (KSTEPS - 1)) * 32;
            n0s[sl] = brow0[kb2 >> 2];
            n1s[sl] = brow1[kb2 >> 2];
            dvs[sl] = *(const float4*)(dl2e + kb2 + co);
        }

        // A fragment via wave-private LDS transpose (same-wave DS ops are ordered)
        short8 af = *(const short8*)&P[l15][quad * 8];

#pragma unroll
        for (int nt = 0; nt < 8; nt++) {
            union { uint4 q; short8 s8; } bf; bf.q = bv[nt];
            acc[nt] = __builtin_amdgcn_mfma_f32_16x16x32_bf16(af, bf.s8, acc[nt], 0, 0, 0);
        }
    }

    // row sums: reduce over the 8 lanes (chunks) covering each row
    ps0 += __shfl_down(ps0, 4, 8); ps0 += __shfl_down(ps0, 2, 8); ps0 += __shfl_down(ps0, 1, 8);
    ps1 += __shfl_down(ps1, 4, 8); ps1 += __shfl_down(ps1, 2, 8); ps1 += __shfl_down(ps1, 1, 8);
    if ((lane & 7) == 0) {
        lp[split * NN + i0 + r0] = ps0;
        lp[split * NN + i0 + r1] = ps1;
    }

    // accumulator partials, lane-major tile layout (fully coalesced)
    float* ab = accp + (size_t)split * (NN * FOUT);
#pragma unroll
    for (int nt = 0; nt < 8; nt++)
        *(f32x4*)&ab[((size_t)(strip * 8 + nt) * 64 + lane) * 4] = acc[nt];
}

// ---------------- K2b: inverse row sums --------------------------------------------
__global__ __launch_bounds__(256) void k2b_rsum(const float* __restrict__ lp,
                                               float* __restrict__ rinv)
{
    int i = blockIdx.x * 256 + threadIdx.x;
    float s = 0.f;
#pragma unroll
    for (int sp = 0; sp < SPLITS; sp++) s += lp[sp * NN + i];
    rinv[i] = 1.0f / s;
}

// ---------------- K3: combine splits from tile layout, normalize, store ------------
__global__ __launch_bounds__(256) void k3_comb(
    const float* __restrict__ accp, const float* __restrict__ rinv, float* __restrict__ out)
{
    int idx = blockIdx.x * 256 + threadIdx.x;   // float4 index over tile storage
    int tile = idx >> 6, l = idx & 63;
    float4 s = make_float4(0.f, 0.f, 0.f, 0.f);
#pragma unroll
    for (int sp = 0; sp < SPLITS; sp++) {
        float4 v = *(const float4*)(accp + (size_t)sp * (NN * FOUT) + (size_t)idx * 4);
        s.x += v.x; s.y += v.y; s.z += v.z; s.w += v.w;
    }
    int row0 = (tile >> 3) * 16 + (l >> 4) * 4;
    int col  = (tile & 7) * 16 + (l & 15);
    float4 ri = *(const float4*)(rinv + row0);
    out[(size_t)(row0 + 0) * FOUT + col] = s.x * ri.x;
    out[(size_t)(row0 + 1) * FOUT + col] = s.y * ri.y;
    out[(size_t)(row0 + 2) * FOUT + col] = s.z * ri.z;
    out[(size_t)(row0 + 3) * FOUT + col] = s.w * ri.w;
}

extern "C" void kernel_launch(void* const* d_in, const int* in_sizes, int n_in,
                              void* d_out, int out_size, void* d_ws, size_t ws_size,
                              hipStream_t stream) {
    const float* h   = (const float*)d_in[0];
    const int*   adj = (const int*)d_in[1];
    const float* W   = (const float*)d_in[2];
    const float* a   = (const float*)d_in[3];
    float* out = (float*)d_out;

    char* ws = (char*)d_ws;
    u16*   whfrag = (u16*)ws;                           // 2 MB
    float* src    = (float*)(ws + (2u << 20));          // 32 KB
    float* dl2e   = src + NN;                           // 32 KB
    u32*   gmaxk  = (u32*)(dl2e + NN);                  // 4 B
    float* accp   = (float*)(ws + (3u << 20));          // 32 MB
    float* lp     = (float*)(ws + (35u << 20));         // 256 KB
    float* rinv   = (float*)(ws + (36u << 20));         // 32 KB
    u8*    bm     = (u8*)(ws + (37u << 20));            // 16 MB nibble-map

    (void)hipMemsetAsync(gmaxk, 0, sizeof(u32), stream);
    k0_pack<<<dim3((NN / 4) * (NN / 256)), dim3(256), 0, stream>>>(adj, bm);
    k1_wh<<<dim3(NN / 32), dim3(256), 0, stream>>>(h, W, a, whfrag, src, dl2e, gmaxk);
    k2_attn<<<dim3(NN / 64, SPLITS), dim3(256), 0, stream>>>(bm, src, dl2e, whfrag, gmaxk, accp, lp);
    k2b_rsum<<<dim3(NN / 256), dim3(256), 0, stream>>>(lp, rinv);
    k3_comb<<<dim3((NN * FOUT / 4) / 256), dim3(256), 0, stream>>>(accp, rinv, out);
}